// Round 13
// baseline (244.439 us; speedup 1.0000x reference)
//
#include <hip/hip_runtime.h>
#include <math.h>

// Problem dims (fixed)
#define NB 16
#define NV 12
#define NROWS 192          // NB*NV
#define DRAW 200704
#define KOUT 256
#define DFEAT 1024
#define NG 8
#define NCLS 40

// K1: 256 blocks, one K-chunk each (KC=784 -> 25 steps of BK=32), full 192x256.
#define NCHUNK 256
#define KC 784

// LDS (bytes), single buffer 57344:
// A: 6 Mtiles(32 rows) x [2 ksubs x (1KB hi + 1KB lo)] = 24576 (bf16 pre-split)
// B: raw f32 [32 k][256 col] = 32768 (split done by consumer waves)
#define ABASE 0
#define BBASE 24576

// workspace layout (bytes)
#define WS_SCORE 0                       // [192] f32
#define WS_PART  4096                    // [192 rows][256 chunks][256 cols] f32

typedef __attribute__((ext_vector_type(8))) short short8;
typedef __attribute__((ext_vector_type(16))) float f32x16;

// split x -> hi(bf16 trunc) + lo(bf16 trunc of exact residual); pack 4 elems
__device__ __forceinline__ void cvt4(float4 v, uint2& hi, uint2& lo) {
    unsigned b0 = __float_as_uint(v.x), b1 = __float_as_uint(v.y);
    unsigned b2 = __float_as_uint(v.z), b3 = __float_as_uint(v.w);
    hi.x = (b0 >> 16) | (b1 & 0xffff0000u);
    hi.y = (b2 >> 16) | (b3 & 0xffff0000u);
    float r0 = v.x - __uint_as_float(b0 & 0xffff0000u);
    float r1 = v.y - __uint_as_float(b1 & 0xffff0000u);
    float r2 = v.z - __uint_as_float(b2 & 0xffff0000u);
    float r3 = v.w - __uint_as_float(b3 & 0xffff0000u);
    lo.x = (__float_as_uint(r0) >> 16) | (__float_as_uint(r1) & 0xffff0000u);
    lo.y = (__float_as_uint(r2) >> 16) | (__float_as_uint(r3) & 0xffff0000u);
}

__device__ __forceinline__ short8 mk8(uint2 a, uint2 b) {
    union { unsigned u[4]; short8 s; } x;
    x.u[0] = a.x; x.u[1] = a.y; x.u[2] = b.x; x.u[3] = b.y;
    return x.s;
}

// issue step-S1 global loads. A: 3 guarded dwordx4 (R12-exact).
// B: 4 LINEAR float4 passes -- pass p covers k-rows p*8+(t>>6), cols (t&63)*4;
// each wave instruction streams 1KB contiguous of W1.
#define K1_LOAD(DA, DB, S1)                                                    \
  {                                                                            \
    const int koff = (S1) * 32;                                                \
    const float4 f4z = make_float4(0.f, 0.f, 0.f, 0.f);                        \
    _Pragma("unroll") for (int p = 0; p < 3; ++p) {                            \
      bool ok = aact[p] && (akq[p] * 4 + koff < KC);                           \
      DA[p] = ok ? *(const float4*)(aptr[p] + koff) : f4z;                     \
    }                                                                          \
    _Pragma("unroll") for (int p = 0; p < 4; ++p) {                            \
      bool ok = (koff + p * 8 + bkk) < KC;                                     \
      DB[p] = ok ? *(const float4*)(bptr + (size_t)(koff + p * 8) * KOUT)      \
                 : f4z;                                                        \
    }                                                                          \
  }

// stage regs -> LDS: A cvt'd to hi/lo bf16 (R12-exact); B raw f32 linear
// (conflict-free: lanes write consecutive 16B).
#define K1_WRITE(CA, CB)                                                       \
  {                                                                            \
    _Pragma("unroll") for (int p = 0; p < 3; ++p) {                            \
      uint2 hi, lo; cvt4(CA[p], hi, lo);                                       \
      *(uint2*)(smem + awoff[p]) = hi;                                         \
      *(uint2*)(smem + awoff[p] + 1024) = lo;                                  \
    }                                                                          \
    _Pragma("unroll") for (int p = 0; p < 4; ++p)                              \
      *(float4*)(smem + bwoff + p * 8192) = CB[p];                             \
  }

// fragment reads + 36 MFMAs of 32x32x16 (2 ksubs x 3x2 frags x bf16x3).
// A: pre-split hi/lo at lane*16 (conflict-free). B: 8 ds_read_b32 from f32
// [k][col] (banks = col%32 -> 2-way max = free), cvt in-register.
#define K1_MMA()                                                               \
  {                                                                            \
    _Pragma("unroll") for (int kf = 0; kf < 2; ++kf) {                         \
      short8 ah[3], al[3];                                                     \
      _Pragma("unroll") for (int tm = 0; tm < 3; ++tm) {                       \
        int off = ABASE + (wm * 3 + tm) * 4096 + kf * 2048 + (lane << 4);      \
        ah[tm] = *(const short8*)(smem + off);                                 \
        al[tm] = *(const short8*)(smem + off + 1024);                          \
      }                                                                        \
      _Pragma("unroll") for (int tn = 0; tn < 2; ++tn) {                       \
        float bq0[4], bq1[4];                                                  \
        _Pragma("unroll") for (int q = 0; q < 4; ++q) {                        \
          bq0[q] = *(const float*)(smem + bro + kf * 16384 + tn * 128 + q * 1024); \
          bq1[q] = *(const float*)(smem + bro + kf * 16384 + tn * 128 + (q + 4) * 1024); \
        }                                                                      \
        uint2 h0, l0, h1, l1;                                                  \
        cvt4(make_float4(bq0[0], bq0[1], bq0[2], bq0[3]), h0, l0);             \
        cvt4(make_float4(bq1[0], bq1[1], bq1[2], bq1[3]), h1, l1);             \
        short8 bh = mk8(h0, h1), bl = mk8(l0, l1);                             \
        _Pragma("unroll") for (int tm = 0; tm < 3; ++tm) {                     \
          acc[tm][tn] = __builtin_amdgcn_mfma_f32_32x32x16_bf16(ah[tm], bh, acc[tm][tn], 0, 0, 0); \
          acc[tm][tn] = __builtin_amdgcn_mfma_f32_32x32x16_bf16(ah[tm], bl, acc[tm][tn], 0, 0, 0); \
          acc[tm][tn] = __builtin_amdgcn_mfma_f32_32x32x16_bf16(al[tm], bh, acc[tm][tn], 0, 0, 0); \
        }                                                                      \
      }                                                                        \
    }                                                                          \
  }

// one K-step (R4/R12-exact discipline): raw top barrier (no vmcnt drain),
// issue next loads (stay in flight through MFMA), stage cur, lgkm+barrier, MMA.
#define K1_STEP(CA, CB, NA, NB_, S, DOLOAD)                                    \
  {                                                                            \
    __builtin_amdgcn_sched_barrier(0);                                         \
    __builtin_amdgcn_s_barrier();                                              \
    __builtin_amdgcn_sched_barrier(0);                                         \
    if (DOLOAD) K1_LOAD(NA, NB_, (S) + 1);                                     \
    K1_WRITE(CA, CB);                                                          \
    asm volatile("s_waitcnt lgkmcnt(0)" ::: "memory");                         \
    __builtin_amdgcn_s_barrier();                                              \
    __builtin_amdgcn_sched_barrier(0);                                         \
    K1_MMA();                                                                  \
  }

// MFMA split-K GEMM, 32x32x16, full-width blocks (R12 structure). Block =
// one K-chunk, entire 192x256 output. 8 waves 2(M)x4(N); wave owns 96x64 =
// 3x2 fragments. bf16x3: acc += ah*bh + ah*bl + al*bh.
__global__ __launch_bounds__(512, 2)
void k1_mfma(const float* __restrict__ raw, const float* __restrict__ W1,
             const int* __restrict__ vnum, float* __restrict__ part)
{
    __shared__ __align__(16) char smem[57344];
    __shared__ char act[NROWS];
    const int t = threadIdx.x;
    const int c = blockIdx.x;
    const int d0 = c * KC;
    if (t < NROWS) act[t] = ((t % NV) < vnum[t / NV]) ? 1 : 0;
    __syncthreads();

    // ---- A staging: 3 passes, idx=p*512+t: row=idx>>3 (0..191), kq=idx&7 ----
    int akq[3];
    bool aact[3];
    const float* aptr[3];
    int awoff[3];
#pragma unroll
    for (int p = 0; p < 3; ++p) {
        int idx = p * 512 + t;
        int row = idx >> 3, kq = idx & 7;
        akq[p] = kq;
        aact[p] = act[row] != 0;
        aptr[p] = raw + (size_t)row * DRAW + d0 + kq * 4;
        awoff[p] = ABASE + (row >> 5) * 4096 + (kq >> 2) * 2048
                 + (((row & 31) + ((kq >> 1) & 1) * 32) << 4) + ((kq & 1) << 3);
    }
    // ---- B staging: linear. kk = t>>6 (k within octet-pass), col4 = t&63 ----
    const int bkk = t >> 6;
    const float* bptr = W1 + (size_t)(d0 + bkk) * KOUT + ((t & 63) << 2);
    const int bwoff = BBASE + (bkk << 10) + ((t & 63) << 4);

    // wave/fragment geometry: 2(M) x 4(N)
    const int lane = t & 63;
    const int wave = t >> 6;
    const int wm = wave >> 2, wn = wave & 3;
    // B fragment f32 read base: col = wn*64 + tn*32 + (lane&31), k = (lane>>5)*8+q
    const int bro = BBASE + ((lane >> 5) << 13) + ((wn * 64 + (lane & 31)) << 2);

    f32x16 acc[3][2];
#pragma unroll
    for (int i = 0; i < 3; ++i)
#pragma unroll
        for (int j = 0; j < 2; ++j)
#pragma unroll
            for (int r = 0; r < 16; ++r) acc[i][j][r] = 0.f;

    float4 A0[3], A1[3];
    float4 B0r[4], B1r[4];
    K1_LOAD(A0, B0r, 0);

#pragma unroll 1
    for (int sp = 0; sp < 12; ++sp) {
        K1_STEP(A0, B0r, A1, B1r, 2 * sp, 1);
        K1_STEP(A1, B1r, A0, B0r, 2 * sp + 1, 1);
    }
    K1_STEP(A0, B0r, A1, B1r, 24, 0);

    // ---- epilogue: part[row][chunk][col]; 32x32 C/D layout (m74/m101):
    // col = lane&31, row = (r&3) + 8*(r>>2) + 4*(lane>>5), r in [0,16)
    const int l31 = lane & 31, lh = lane >> 5;
#pragma unroll
    for (int tm = 0; tm < 3; ++tm) {
        int rowb = wm * 96 + tm * 32 + 4 * lh;
#pragma unroll
        for (int tn = 0; tn < 2; ++tn) {
            int colx = wn * 64 + tn * 32 + l31;
            f32x16 a = acc[tm][tn];
#pragma unroll
            for (int r = 0; r < 16; ++r) {
                int grow = rowb + (r & 3) + 8 * (r >> 2);
                part[((size_t)grow * NCHUNK + c) * KOUT + colx] = a[r];
            }
        }
    }
}

// fused 256-chunk reduce + score head. One block per row; part[row] is a
// CONTIGUOUS 256KB stream -> coalesced. (verified R7/R10/R11/R12)
__global__ __launch_bounds__(1024)
void k2_score(const float* __restrict__ part, const float* __restrict__ b1,
              const float* __restrict__ W2, const float* __restrict__ b2,
              float* __restrict__ score)
{
    const int row = blockIdx.x, t = threadIdx.x;
    const int col = t & 255, cg = t >> 8;
    __shared__ float red[4][KOUT];
    __shared__ float r2[4];
    const float* p = part + ((size_t)row * NCHUNK + cg * 64) * KOUT + col;
    float s = 0.f;
#pragma unroll 8
    for (int i = 0; i < 64; ++i) s += p[(size_t)i * KOUT];
    red[cg][col] = s;
    __syncthreads();
    if (t < 256) {
        float v = red[0][col] + red[1][col] + red[2][col] + red[3][col];
        float h = fmaxf(v + b1[col], 0.f) * W2[col];
        for (int o = 32; o > 0; o >>= 1) h += __shfl_down(h, o, 64);
        if ((t & 63) == 0) r2[t >> 6] = h;
    }
    __syncthreads();
    if (t == 0) {
        float sm = r2[0] + r2[1] + r2[2] + r2[3];
        float sraw = fmaxf(sm + b2[0], 0.f);
        score[row] = 1.f / (1.f + expf(-tanhf(fabsf(sraw))));
    }
}

// fused tail: binning->coeff->desc->3-layer classifier. One block per sample.
// (verified R4/R9/R11/R12)
__global__ __launch_bounds__(512)
void k5f(const float* __restrict__ score, const int* __restrict__ vnum,
         const float* __restrict__ fv,
         const float* __restrict__ Wf1, const float* __restrict__ bf1,
         const float* __restrict__ Wf2, const float* __restrict__ bf2,
         const float* __restrict__ Wl,  const float* __restrict__ bl,
         float* __restrict__ out)
{
    const int n = blockIdx.x, t = threadIdx.x;
    __shared__ float coeffL[NV], descL[DFEAT], z1L[512], z2L[256];
    __shared__ float wsum[NG], wt[NG], outred[8][NCLS];
    __shared__ int cnt[NG];
    __shared__ float wtotS;
    if (t < NG) { cnt[t] = 0; wsum[t] = 0.f; }
    __syncthreads();
    const int vn = vnum[n];
    const bool act = (t < NV) && (t < vn);
    float sc = 0.f; int b = 0;
    if (act) {
        sc = score[n * NV + t];
        b = (int)floorf(sc * 8.f); b = b < 0 ? 0 : (b > 7 ? 7 : b);
        atomicAdd(&cnt[b], 1);
    }
    __syncthreads();
    if (act) atomicAdd(&wsum[b], ceilf(sc * (float)cnt[b]));
    __syncthreads();
    if (t < NG) wt[t] = (cnt[t] > 0) ? wsum[t] / (float)cnt[t] : 0.f;
    __syncthreads();
    if (t == 0) { float x = 0.f; for (int g = 0; g < NG; ++g) x += wt[g]; wtotS = x; }
    __syncthreads();
    if (t < NV) coeffL[t] = act ? wt[b] / ((float)cnt[b] * wtotS) : 0.f;
    __syncthreads();
#pragma unroll
    for (int p = 0; p < 2; ++p) {
        int d = t + p * 512;
        float a = 0.f;
#pragma unroll
        for (int v = 0; v < NV; ++v)
            a = fmaf(coeffL[v], fv[((size_t)n * NV + v) * DFEAT + d], a);
        descL[d] = a;
    }
    __syncthreads();
    {
        float a = 0.f;
#pragma unroll 8
        for (int d = 0; d < DFEAT; ++d)
            a = fmaf(descL[d], Wf1[(size_t)d * 512 + t], a);
        z1L[t] = fmaxf(a + bf1[t], 0.f);
    }
    __syncthreads();
    if (t < 256) {
        float a = 0.f;
#pragma unroll 8
        for (int d = 0; d < 512; ++d)
            a = fmaf(z1L[d], Wf2[(size_t)d * 256 + t], a);
        z2L[t] = fmaxf(a + bf2[t], 0.f);
    }
    __syncthreads();
    if (t < 320) {
        int j = t % NCLS, seg = t / NCLS;
        float a = 0.f;
#pragma unroll
        for (int dd = 0; dd < 32; ++dd) {
            int d = seg * 32 + dd;
            a = fmaf(z2L[d], Wl[d * NCLS + j], a);
        }
        outred[seg][j] = a;
    }
    __syncthreads();
    if (t < NCLS) {
        float a = bl[t];
#pragma unroll
        for (int s8 = 0; s8 < 8; ++s8) a += outred[s8][t];
        out[n * NCLS + t] = a;
    }
}

extern "C" void kernel_launch(void* const* d_in, const int* in_sizes, int n_in,
                              void* d_out, int out_size, void* d_ws, size_t ws_size,
                              hipStream_t stream)
{
    const float* raw  = (const float*)d_in[0];
    const float* fv   = (const float*)d_in[1];
    const int*   vnum = (const int*)d_in[2];
    const float* W1   = (const float*)d_in[3];
    const float* b1   = (const float*)d_in[4];
    const float* W2   = (const float*)d_in[5];
    const float* b2   = (const float*)d_in[6];
    const float* Wf1  = (const float*)d_in[7];
    const float* bf1  = (const float*)d_in[8];
    const float* Wf2  = (const float*)d_in[9];
    const float* bf2  = (const float*)d_in[10];
    const float* Wl   = (const float*)d_in[11];
    const float* bl   = (const float*)d_in[12];
    float* out = (float*)d_out;
    char* ws = (char*)d_ws;
    float* score = (float*)(ws + WS_SCORE);
    float* part  = (float*)(ws + WS_PART);

    k1_mfma<<<NCHUNK, 512, 0, stream>>>(raw, W1, vnum, part);
    k2_score<<<NROWS, 1024, 0, stream>>>(part, b1, W2, b2, score);
    k5f<<<NB, 512, 0, stream>>>(score, vnum, fv, Wf1, bf1, Wf2, bf2, Wl, bl, out);
}

// Round 14
// 197.590 us; speedup vs baseline: 1.2371x; 1.2371x over previous
//
#include <hip/hip_runtime.h>
#include <math.h>

// Problem dims (fixed)
#define NB 16
#define NV 12
#define NROWS 192          // NB*NV
#define DRAW 200704
#define KOUT 256
#define DFEAT 1024
#define NG 8
#define NCLS 40

// K1: 512 blocks = 256 K-chunks x 2 col-halves. KC=784 -> 25 steps of BK=32.
#define NCHUNK 256
#define KC 784

// LDS (bytes) 57344, 2 blocks/CU:
// A: 6 Mtiles(32 rows) x [2 ksubs x (1KB hi + 1KB lo)] = 24576 (bf16 pre-split)
// B: DOUBLE-buffered raw f32 [32 k][128 col] = 2 x 16384 (DMA'd, consumer cvt)
#define ABASE 0
#define BBASE 24576

// workspace layout (bytes)
#define WS_SCORE 0                       // [192] f32
#define WS_PART  4096                    // [192 rows][256 chunks][256 cols] f32

typedef __attribute__((ext_vector_type(8))) short short8;
typedef __attribute__((ext_vector_type(16))) float f32x16;

// split x -> hi(bf16 trunc) + lo(bf16 trunc of exact residual); pack 4 elems
__device__ __forceinline__ void cvt4(float4 v, uint2& hi, uint2& lo) {
    unsigned b0 = __float_as_uint(v.x), b1 = __float_as_uint(v.y);
    unsigned b2 = __float_as_uint(v.z), b3 = __float_as_uint(v.w);
    hi.x = (b0 >> 16) | (b1 & 0xffff0000u);
    hi.y = (b2 >> 16) | (b3 & 0xffff0000u);
    float r0 = v.x - __uint_as_float(b0 & 0xffff0000u);
    float r1 = v.y - __uint_as_float(b1 & 0xffff0000u);
    float r2 = v.z - __uint_as_float(b2 & 0xffff0000u);
    float r3 = v.w - __uint_as_float(b3 & 0xffff0000u);
    lo.x = (__float_as_uint(r0) >> 16) | (__float_as_uint(r1) & 0xffff0000u);
    lo.y = (__float_as_uint(r2) >> 16) | (__float_as_uint(r3) & 0xffff0000u);
}

__device__ __forceinline__ short8 mk8(uint2 a, uint2 b) {
    union { unsigned u[4]; short8 s; } x;
    x.u[0] = a.x; x.u[1] = a.y; x.u[2] = b.x; x.u[3] = b.y;
    return x.s;
}

// B staging via global_load_lds DMA: 2 instrs/wave, each streams 1KB (2 k-rows
// x 128 f32) from W1 (per-lane coalesced source) to linear LDS [k][col4]
// (wave-uniform dest base + lane*16). No VGPRs, no staging cvt.
// Tail validity: source row clamped in-bounds; A's k-guard zeroes products.
#define K1_BDMA(S1, WB)                                                        \
  {                                                                            \
    const int koff = (S1) * 32;                                                \
    _Pragma("unroll") for (int p = 0; p < 2; ++p) {                            \
      int kl = (wave << 2) + (p << 1) + (lane >> 5);                           \
      int kg = koff + kl;                                                      \
      kg = (kg < KC) ? kg : (KC - 1);                                          \
      const float* g = W1 + (size_t)(d0 + kg) * KOUT + colbase + ((lane & 31) << 2); \
      char* l = smem + BBASE + (WB) + (((wave << 2) + (p << 1)) << 9);         \
      __builtin_amdgcn_global_load_lds(                                        \
          (const __attribute__((address_space(1))) void*)g,                    \
          (__attribute__((address_space(3))) void*)l, 16, 0, 0);               \
    }                                                                          \
  }

// A reg loads for step S1 (R4-exact guards)
#define K1_ALOAD(DA, S1)                                                       \
  {                                                                            \
    const int koff = (S1) * 32;                                                \
    _Pragma("unroll") for (int p = 0; p < 3; ++p) {                            \
      bool ok = aact[p] && (akq[p] * 4 + koff < KC);                           \
      DA[p] = ok ? *(const float4*)(aptr[p] + koff)                            \
                 : make_float4(0.f, 0.f, 0.f, 0.f);                            \
    }                                                                          \
  }

// A cvt regs -> LDS (bf16 hi/lo pre-split, R12-exact layout)
#define K1_AWRITE(CA)                                                          \
  {                                                                            \
    _Pragma("unroll") for (int p = 0; p < 3; ++p) {                            \
      uint2 hi, lo; cvt4(CA[p], hi, lo);                                       \
      *(uint2*)(smem + awoff[p]) = hi;                                         \
      *(uint2*)(smem + awoff[p] + 1024) = lo;                                  \
    }                                                                          \
  }

// fragment reads + 18 MFMAs of 32x32x16 (2 ksubs x 3 M-frags x bf16x3).
// A: pre-split hi/lo at lane*16 (conflict-free). B: 16 ds_read_b32 from f32
// [k][col] (banks = col%32 -> 2-way = free), cvt in-register (overlaps MFMA).
#define K1_MMA(RB)                                                             \
  {                                                                            \
    _Pragma("unroll") for (int kf = 0; kf < 2; ++kf) {                         \
      short8 ah[3], al[3];                                                     \
      _Pragma("unroll") for (int tm = 0; tm < 3; ++tm) {                       \
        int off = ABASE + (wm * 3 + tm) * 4096 + kf * 2048 + (lane << 4);      \
        ah[tm] = *(const short8*)(smem + off);                                 \
        al[tm] = *(const short8*)(smem + off + 1024);                          \
      }                                                                        \
      float bq0[4], bq1[4];                                                    \
      _Pragma("unroll") for (int q = 0; q < 4; ++q) {                          \
        bq0[q] = *(const float*)(smem + bro + (RB) + kf * 8192 + q * 512);     \
        bq1[q] = *(const float*)(smem + bro + (RB) + kf * 8192 + (q + 4) * 512); \
      }                                                                        \
      uint2 h0, l0, h1, l1;                                                    \
      cvt4(make_float4(bq0[0], bq0[1], bq0[2], bq0[3]), h0, l0);               \
      cvt4(make_float4(bq1[0], bq1[1], bq1[2], bq1[3]), h1, l1);               \
      short8 bh = mk8(h0, h1), bl = mk8(l0, l1);                               \
      _Pragma("unroll") for (int tm = 0; tm < 3; ++tm) {                       \
        acc[tm] = __builtin_amdgcn_mfma_f32_32x32x16_bf16(ah[tm], bh, acc[tm], 0, 0, 0); \
        acc[tm] = __builtin_amdgcn_mfma_f32_32x32x16_bf16(ah[tm], bl, acc[tm], 0, 0, 0); \
        acc[tm] = __builtin_amdgcn_mfma_f32_32x32x16_bf16(al[tm], bh, acc[tm], 0, 0, 0); \
      }                                                                        \
    }                                                                          \
  }

// one K-step: raw top barrier (A rewrite safe; B dbuf disjoint), issue B-DMA
// (s+1 -> WB) + A-loads (s+1), A cvt+write (s), COUNTED vmcnt(5): drains last
// step's B-DMA while keeping this step's 5 newest (2 DMA + 3 A) in flight.
#define K1_STEP(CA, NA, RB, WB, S, DOLOAD)                                     \
  {                                                                            \
    __builtin_amdgcn_sched_barrier(0);                                         \
    __builtin_amdgcn_s_barrier();                                              \
    __builtin_amdgcn_sched_barrier(0);                                         \
    if (DOLOAD) { K1_BDMA((S) + 1, WB); K1_ALOAD(NA, (S) + 1); }               \
    K1_AWRITE(CA);                                                             \
    if (DOLOAD) { asm volatile("s_waitcnt vmcnt(5) lgkmcnt(0)" ::: "memory"); }\
    else        { asm volatile("s_waitcnt vmcnt(0) lgkmcnt(0)" ::: "memory"); }\
    __builtin_amdgcn_s_barrier();                                              \
    __builtin_amdgcn_sched_barrier(0);                                         \
    K1_MMA(RB);                                                                \
  }

// MFMA split-K/split-N GEMM, 32x32x16, B via global_load_lds DMA. Co-XCD bid
// map: both col-halves of a chunk share bid%8 (same XCD L2 for A reuse).
// 8 waves 2(M)x4(N); wave owns 96 rows x 32 cols = 3 fragments of 32x32.
// bf16x3: acc += ah*bh + ah*bl + al*bh.
__global__ __launch_bounds__(512, 4)
void k1_mfma(const float* __restrict__ raw, const float* __restrict__ W1,
             const int* __restrict__ vnum, float* __restrict__ part)
{
    __shared__ __align__(16) char smem[57344];
    __shared__ char act[NROWS];
    const int t = threadIdx.x;
    const int g8 = blockIdx.x & 7;
    const int i8 = blockIdx.x >> 3;
    const int c = g8 * 32 + (i8 >> 1);
    const int colbase = (i8 & 1) * 128;
    const int d0 = c * KC;
    if (t < NROWS) act[t] = ((t % NV) < vnum[t / NV]) ? 1 : 0;
    __syncthreads();

    // ---- A staging: 3 passes, idx=p*512+t: row=idx>>3 (0..191), kq=idx&7 ----
    int akq[3];
    bool aact[3];
    const float* aptr[3];
    int awoff[3];
#pragma unroll
    for (int p = 0; p < 3; ++p) {
        int idx = p * 512 + t;
        int row = idx >> 3, kq = idx & 7;
        akq[p] = kq;
        aact[p] = act[row] != 0;
        aptr[p] = raw + (size_t)row * DRAW + d0 + kq * 4;
        awoff[p] = ABASE + (row >> 5) * 4096 + (kq >> 2) * 2048
                 + (((row & 31) + ((kq >> 1) & 1) * 32) << 4) + ((kq & 1) << 3);
    }

    // wave/fragment geometry: 2(M) x 4(N)
    const int lane = t & 63;
    const int wave = t >> 6;
    const int wm = wave >> 2, wn = wave & 3;
    const int l31 = lane & 31, lh = lane >> 5;
    // B fragment f32 read base: col = wn*32 + l31, k = kf*16 + lh*8 + q
    const int bro = BBASE + (lh << 12) + ((wn * 32 + l31) << 2);

    f32x16 acc[3];
#pragma unroll
    for (int i = 0; i < 3; ++i)
#pragma unroll
        for (int r = 0; r < 16; ++r) acc[i][r] = 0.f;

    float4 A0[3], A1[3];
    K1_BDMA(0, 0);
    K1_ALOAD(A0, 0);

#pragma unroll 1
    for (int sp = 0; sp < 12; ++sp) {
        K1_STEP(A0, A1, 0, 16384, 2 * sp, 1);
        K1_STEP(A1, A0, 16384, 0, 2 * sp + 1, 1);
    }
    K1_STEP(A0, A1, 0, 16384, 24, 0);

    // ---- epilogue: part[row][chunk][col]; 32x32 C/D layout (m74/m101):
    // col = lane&31, row = (r&3) + 8*(r>>2) + 4*(lane>>5), r in [0,16)
#pragma unroll
    for (int tm = 0; tm < 3; ++tm) {
        int rowb = wm * 96 + tm * 32 + 4 * lh;
        int colx = colbase + wn * 32 + l31;
        f32x16 a = acc[tm];
#pragma unroll
        for (int r = 0; r < 16; ++r) {
            int grow = rowb + (r & 3) + 8 * (r >> 2);
            part[((size_t)grow * NCHUNK + c) * KOUT + colx] = a[r];
        }
    }
}

// fused 256-chunk reduce + score head. One block per row; part[row] is a
// CONTIGUOUS 256KB stream -> coalesced. (verified R7/R10/R11/R12)
__global__ __launch_bounds__(1024)
void k2_score(const float* __restrict__ part, const float* __restrict__ b1,
              const float* __restrict__ W2, const float* __restrict__ b2,
              float* __restrict__ score)
{
    const int row = blockIdx.x, t = threadIdx.x;
    const int col = t & 255, cg = t >> 8;
    __shared__ float red[4][KOUT];
    __shared__ float r2[4];
    const float* p = part + ((size_t)row * NCHUNK + cg * 64) * KOUT + col;
    float s = 0.f;
#pragma unroll 8
    for (int i = 0; i < 64; ++i) s += p[(size_t)i * KOUT];
    red[cg][col] = s;
    __syncthreads();
    if (t < 256) {
        float v = red[0][col] + red[1][col] + red[2][col] + red[3][col];
        float h = fmaxf(v + b1[col], 0.f) * W2[col];
        for (int o = 32; o > 0; o >>= 1) h += __shfl_down(h, o, 64);
        if ((t & 63) == 0) r2[t >> 6] = h;
    }
    __syncthreads();
    if (t == 0) {
        float sm = r2[0] + r2[1] + r2[2] + r2[3];
        float sraw = fmaxf(sm + b2[0], 0.f);
        score[row] = 1.f / (1.f + expf(-tanhf(fabsf(sraw))));
    }
}

// fused tail: binning->coeff->desc->3-layer classifier. One block per sample.
// (verified R4/R9/R11/R12)
__global__ __launch_bounds__(512)
void k5f(const float* __restrict__ score, const int* __restrict__ vnum,
         const float* __restrict__ fv,
         const float* __restrict__ Wf1, const float* __restrict__ bf1,
         const float* __restrict__ Wf2, const float* __restrict__ bf2,
         const float* __restrict__ Wl,  const float* __restrict__ bl,
         float* __restrict__ out)
{
    const int n = blockIdx.x, t = threadIdx.x;
    __shared__ float coeffL[NV], descL[DFEAT], z1L[512], z2L[256];
    __shared__ float wsum[NG], wt[NG], outred[8][NCLS];
    __shared__ int cnt[NG];
    __shared__ float wtotS;
    if (t < NG) { cnt[t] = 0; wsum[t] = 0.f; }
    __syncthreads();
    const int vn = vnum[n];
    const bool act = (t < NV) && (t < vn);
    float sc = 0.f; int b = 0;
    if (act) {
        sc = score[n * NV + t];
        b = (int)floorf(sc * 8.f); b = b < 0 ? 0 : (b > 7 ? 7 : b);
        atomicAdd(&cnt[b], 1);
    }
    __syncthreads();
    if (act) atomicAdd(&wsum[b], ceilf(sc * (float)cnt[b]));
    __syncthreads();
    if (t < NG) wt[t] = (cnt[t] > 0) ? wsum[t] / (float)cnt[t] : 0.f;
    __syncthreads();
    if (t == 0) { float x = 0.f; for (int g = 0; g < NG; ++g) x += wt[g]; wtotS = x; }
    __syncthreads();
    if (t < NV) coeffL[t] = act ? wt[b] / ((float)cnt[b] * wtotS) : 0.f;
    __syncthreads();
#pragma unroll
    for (int p = 0; p < 2; ++p) {
        int d = t + p * 512;
        float a = 0.f;
#pragma unroll
        for (int v = 0; v < NV; ++v)
            a = fmaf(coeffL[v], fv[((size_t)n * NV + v) * DFEAT + d], a);
        descL[d] = a;
    }
    __syncthreads();
    {
        float a = 0.f;
#pragma unroll 8
        for (int d = 0; d < DFEAT; ++d)
            a = fmaf(descL[d], Wf1[(size_t)d * 512 + t], a);
        z1L[t] = fmaxf(a + bf1[t], 0.f);
    }
    __syncthreads();
    if (t < 256) {
        float a = 0.f;
#pragma unroll 8
        for (int d = 0; d < 512; ++d)
            a = fmaf(z1L[d], Wf2[(size_t)d * 256 + t], a);
        z2L[t] = fmaxf(a + bf2[t], 0.f);
    }
    __syncthreads();
    if (t < 320) {
        int j = t % NCLS, seg = t / NCLS;
        float a = 0.f;
#pragma unroll
        for (int dd = 0; dd < 32; ++dd) {
            int d = seg * 32 + dd;
            a = fmaf(z2L[d], Wl[d * NCLS + j], a);
        }
        outred[seg][j] = a;
    }
    __syncthreads();
    if (t < NCLS) {
        float a = bl[t];
#pragma unroll
        for (int s8 = 0; s8 < 8; ++s8) a += outred[s8][t];
        out[n * NCLS + t] = a;
    }
}

extern "C" void kernel_launch(void* const* d_in, const int* in_sizes, int n_in,
                              void* d_out, int out_size, void* d_ws, size_t ws_size,
                              hipStream_t stream)
{
    const float* raw  = (const float*)d_in[0];
    const float* fv   = (const float*)d_in[1];
    const int*   vnum = (const int*)d_in[2];
    const float* W1   = (const float*)d_in[3];
    const float* b1   = (const float*)d_in[4];
    const float* W2   = (const float*)d_in[5];
    const float* b2   = (const float*)d_in[6];
    const float* Wf1  = (const float*)d_in[7];
    const float* bf1  = (const float*)d_in[8];
    const float* Wf2  = (const float*)d_in[9];
    const float* bf2  = (const float*)d_in[10];
    const float* Wl   = (const float*)d_in[11];
    const float* bl   = (const float*)d_in[12];
    float* out = (float*)d_out;
    char* ws = (char*)d_ws;
    float* score = (float*)(ws + WS_SCORE);
    float* part  = (float*)(ws + WS_PART);

    k1_mfma<<<2 * NCHUNK, 512, 0, stream>>>(raw, W1, vnum, part);
    k2_score<<<NROWS, 1024, 0, stream>>>(part, b1, W2, b2, score);
    k5f<<<NB, 512, 0, stream>>>(score, vnum, fv, Wf1, bf1, Wf2, bf2, Wl, bl, out);
}

// Round 15
// 144.082 us; speedup vs baseline: 1.6965x; 1.3714x over previous
//
#include <hip/hip_runtime.h>
#include <math.h>

// Problem dims (fixed)
#define NB 16
#define NV 12
#define NROWS 192          // NB*NV
#define DRAW 200704
#define KOUT 256
#define DFEAT 1024
#define NG 8
#define NCLS 40

// K1: 256 blocks, one K-chunk each (KC=784 -> 25 steps of BK=32), full 192x256.
#define NCHUNK 256
#define KC 784

// LDS (bytes), single buffer 57344:
// A: 6 Mtiles(32 rows) x [2 ksubs x (1KB hi + 1KB lo)] = 24576
// B: 8 Ntiles(32 cols) x [2 ksubs x (1KB hi + 1KB lo)] = 32768
#define ABASE 0
#define BBASE 24576

// workspace layout (bytes)
#define WS_PART 0                        // [192 rows][256 chunks][256 cols] f32 (50.3 MB)
#define WS_HR   50331648                 // [192][2][256] f32 half-row sums
#define WS_Z1   50724864                 // [16][512] f32

typedef __attribute__((ext_vector_type(8))) short short8;
typedef __attribute__((ext_vector_type(16))) float f32x16;

// split x -> hi(bf16 trunc) + lo(bf16 trunc of exact residual); pack 4 elems
__device__ __forceinline__ void cvt4(float4 v, uint2& hi, uint2& lo) {
    unsigned b0 = __float_as_uint(v.x), b1 = __float_as_uint(v.y);
    unsigned b2 = __float_as_uint(v.z), b3 = __float_as_uint(v.w);
    hi.x = (b0 >> 16) | (b1 & 0xffff0000u);
    hi.y = (b2 >> 16) | (b3 & 0xffff0000u);
    float r0 = v.x - __uint_as_float(b0 & 0xffff0000u);
    float r1 = v.y - __uint_as_float(b1 & 0xffff0000u);
    float r2 = v.z - __uint_as_float(b2 & 0xffff0000u);
    float r3 = v.w - __uint_as_float(b3 & 0xffff0000u);
    lo.x = (__float_as_uint(r0) >> 16) | (__float_as_uint(r1) & 0xffff0000u);
    lo.y = (__float_as_uint(r2) >> 16) | (__float_as_uint(r3) & 0xffff0000u);
}

// issue step-S1 global loads into named reg buffers (guards R4-style)
#define K1_LOAD(DA, DB, S1)                                                    \
  {                                                                            \
    const int koff = (S1) * 32;                                                \
    _Pragma("unroll") for (int p = 0; p < 3; ++p) {                            \
      bool ok = aact[p] && (akq[p] * 4 + koff < KC);                           \
      DA[p] = ok ? *(const float4*)(aptr[p] + koff)                            \
                 : make_float4(0.f, 0.f, 0.f, 0.f);                            \
    }                                                                          \
    _Pragma("unroll") for (int q = 0; q < 16; ++q) {                           \
      int dd = ks + q + koff;                                                  \
      DB[q] = (dd < KC) ? bptr[(size_t)(koff + q) * KOUT] : 0.f;               \
    }                                                                          \
  }

// cvt regs -> LDS (single buffer)
#define K1_WRITE(CA, CB)                                                       \
  {                                                                            \
    _Pragma("unroll") for (int p = 0; p < 3; ++p) {                            \
      uint2 hi, lo; cvt4(CA[p], hi, lo);                                       \
      *(uint2*)(smem + awoff[p]) = hi;                                         \
      *(uint2*)(smem + awoff[p] + 1024) = lo;                                  \
    }                                                                          \
    _Pragma("unroll") for (int og = 0; og < 2; ++og) {                         \
      uint2 h0, l0, h1, l1;                                                    \
      cvt4(make_float4(CB[og*8+0], CB[og*8+1], CB[og*8+2], CB[og*8+3]), h0, l0); \
      cvt4(make_float4(CB[og*8+4], CB[og*8+5], CB[og*8+6], CB[og*8+7]), h1, l1); \
      uint4 hv; hv.x = h0.x; hv.y = h0.y; hv.z = h1.x; hv.w = h1.y;            \
      uint4 lv; lv.x = l0.x; lv.y = l0.y; lv.z = l1.x; lv.w = l1.y;            \
      *(uint4*)(smem + bwoff[og]) = hv;                                        \
      *(uint4*)(smem + bwoff[og] + 1024) = lv;                                 \
    }                                                                          \
  }

// fragment reads (all at lane*16: conflict-free) + 36 MFMAs of 32x32x16
// (2 ksubs x 3x2 frag-pairs x bf16x3)
#define K1_MMA()                                                               \
  {                                                                            \
    _Pragma("unroll") for (int kf = 0; kf < 2; ++kf) {                         \
      short8 ah[3], al[3];                                                     \
      _Pragma("unroll") for (int tm = 0; tm < 3; ++tm) {                       \
        int off = ABASE + (wm * 3 + tm) * 4096 + kf * 2048 + (lane << 4);      \
        ah[tm] = *(const short8*)(smem + off);                                 \
        al[tm] = *(const short8*)(smem + off + 1024);                          \
      }                                                                        \
      _Pragma("unroll") for (int tn = 0; tn < 2; ++tn) {                       \
        int off = BBASE + (wn * 2 + tn) * 4096 + kf * 2048 + (lane << 4);      \
        short8 bh = *(const short8*)(smem + off);                              \
        short8 bl = *(const short8*)(smem + off + 1024);                       \
        _Pragma("unroll") for (int tm = 0; tm < 3; ++tm) {                     \
          acc[tm][tn] = __builtin_amdgcn_mfma_f32_32x32x16_bf16(ah[tm], bh, acc[tm][tn], 0, 0, 0); \
          acc[tm][tn] = __builtin_amdgcn_mfma_f32_32x32x16_bf16(ah[tm], bl, acc[tm][tn], 0, 0, 0); \
          acc[tm][tn] = __builtin_amdgcn_mfma_f32_32x32x16_bf16(al[tm], bh, acc[tm][tn], 0, 0, 0); \
        }                                                                      \
      }                                                                        \
    }                                                                          \
  }

// one K-step (R4-exact discipline): raw top barrier (no vmcnt drain), issue
// next loads (stay in flight through MFMA), cvt+stage cur, lgkm+barrier, MMA.
#define K1_STEP(CA, CB, NA, NB_, S, DOLOAD)                                    \
  {                                                                            \
    __builtin_amdgcn_sched_barrier(0);                                         \
    __builtin_amdgcn_s_barrier();                                              \
    __builtin_amdgcn_sched_barrier(0);                                         \
    if (DOLOAD) K1_LOAD(NA, NB_, (S) + 1);                                     \
    K1_WRITE(CA, CB);                                                          \
    asm volatile("s_waitcnt lgkmcnt(0)" ::: "memory");                         \
    __builtin_amdgcn_s_barrier();                                              \
    __builtin_amdgcn_sched_barrier(0);                                         \
    K1_MMA();                                                                  \
  }

// MFMA split-K GEMM, 32x32x16, full-width blocks (R12-exact, best measured).
__global__ __launch_bounds__(512, 2)
void k1_mfma(const float* __restrict__ raw, const float* __restrict__ W1,
             const int* __restrict__ vnum, float* __restrict__ part)
{
    __shared__ __align__(16) char smem[57344];
    __shared__ char act[NROWS];
    const int t = threadIdx.x;
    const int c = blockIdx.x;
    const int d0 = c * KC;
    if (t < NROWS) act[t] = ((t % NV) < vnum[t / NV]) ? 1 : 0;
    __syncthreads();

    // ---- A staging: 3 passes, idx=p*512+t: row=idx>>3 (0..191), kq=idx&7 ----
    int akq[3];
    bool aact[3];
    const float* aptr[3];
    int awoff[3];
#pragma unroll
    for (int p = 0; p < 3; ++p) {
        int idx = p * 512 + t;
        int row = idx >> 3, kq = idx & 7;
        akq[p] = kq;
        aact[p] = act[row] != 0;
        aptr[p] = raw + (size_t)row * DRAW + d0 + kq * 4;
        awoff[p] = ABASE + (row >> 5) * 4096 + (kq >> 2) * 2048
                 + (((row & 31) + ((kq >> 1) & 1) * 32) << 4) + ((kq & 1) << 3);
    }
    // ---- B staging: col = t&255, khalf = t>>8 (16 k each) ----
    const int col = t & 255;
    const int khalf = t >> 8;
    const int ks = khalf * 16;
    const float* bptr = W1 + (size_t)(d0 + ks) * KOUT + col;
    int bwoff[2];
#pragma unroll
    for (int og = 0; og < 2; ++og)
        bwoff[og] = BBASE + ((col >> 5) << 12) + (khalf << 11)
                  + (((col & 31) + og * 32) << 4);

    // wave/fragment geometry: 2(M) x 4(N)
    const int lane = t & 63;
    const int wave = t >> 6;
    const int wm = wave >> 2, wn = wave & 3;

    f32x16 acc[3][2];
#pragma unroll
    for (int i = 0; i < 3; ++i)
#pragma unroll
        for (int j = 0; j < 2; ++j)
#pragma unroll
            for (int r = 0; r < 16; ++r) acc[i][j][r] = 0.f;

    float4 A0[3], A1[3];
    float B0r[16], B1r[16];
    K1_LOAD(A0, B0r, 0);

#pragma unroll 1
    for (int sp = 0; sp < 12; ++sp) {
        K1_STEP(A0, B0r, A1, B1r, 2 * sp, 1);
        K1_STEP(A1, B1r, A0, B0r, 2 * sp + 1, 1);
    }
    K1_STEP(A0, B0r, A1, B1r, 24, 0);

    // ---- epilogue: part[row][chunk][col]; 32x32 C/D layout (m74/m101):
    // col = lane&31, row = (r&3) + 8*(r>>2) + 4*(lane>>5), r in [0,16)
    const int l31 = lane & 31, lh = lane >> 5;
#pragma unroll
    for (int tm = 0; tm < 3; ++tm) {
        int rowb = wm * 96 + tm * 32 + 4 * lh;
#pragma unroll
        for (int tn = 0; tn < 2; ++tn) {
            int colx = wn * 64 + tn * 32 + l31;
            f32x16 a = acc[tm][tn];
#pragma unroll
            for (int r = 0; r < 16; ++r) {
                int grow = rowb + (r & 3) + 8 * (r >> 2);
                part[((size_t)grow * NCHUNK + c) * KOUT + colx] = a[r];
            }
        }
    }
}

// half-row reduce: block = (row, half); sums 128 contiguous chunks ->
// hr[row][half][col]. 384 blocks (2x the CU coverage of the old 192).
__global__ __launch_bounds__(1024)
void k2_half(const float* __restrict__ part, float* __restrict__ hr)
{
    const int row = blockIdx.x >> 1, half = blockIdx.x & 1, t = threadIdx.x;
    const int col = t & 255, cg = t >> 8;
    __shared__ float red[4][KOUT];
    const float* p = part + ((size_t)row * NCHUNK + half * 128 + cg * 32) * KOUT + col;
    float s = 0.f;
#pragma unroll 8
    for (int i = 0; i < 32; ++i) s += p[(size_t)i * KOUT];
    red[cg][col] = s;
    __syncthreads();
    if (t < 256)
        hr[((size_t)row * 2 + half) * KOUT + col] =
            red[0][col] + red[1][col] + red[2][col] + red[3][col];
}

// kA: 64 blocks = 16 samples x 4 j-slices. Per block: finish 12 row-scores
// (hr halves add + relu.W2 head), bins->coeff->desc (k5f-verbatim logic),
// then the block's 128-col slice of z1 -> Wf1 read exactly ONCE chip-wide.
__global__ __launch_bounds__(512)
void kA(const float* __restrict__ hr, const float* __restrict__ b1,
        const float* __restrict__ W2, const float* __restrict__ b2,
        const int* __restrict__ vnum, const float* __restrict__ fv,
        const float* __restrict__ Wf1, const float* __restrict__ bf1,
        float* __restrict__ z1)
{
    const int n = blockIdx.x >> 2;
    const int js = (blockIdx.x & 3) * 128;
    const int t = threadIdx.x;
    __shared__ float red4[4], sc_s[NV], coeffL[NV], wsum[NG], wt[NG], wtotS;
    __shared__ int cnt[NG];
    __shared__ float descL[DFEAT];
    __shared__ float zred[4][128];
    // ---- scores for 12 rows ----
    for (int v = 0; v < NV; ++v) {
        if (t < 256) {
            int row = n * NV + v;
            float s = hr[((size_t)row * 2 + 0) * KOUT + t]
                    + hr[((size_t)row * 2 + 1) * KOUT + t];
            float val = fmaxf(s + b1[t], 0.f) * W2[t];
            for (int o = 32; o > 0; o >>= 1) val += __shfl_down(val, o, 64);
            if ((t & 63) == 0) red4[t >> 6] = val;
        }
        __syncthreads();
        if (t == 0) {
            float sm = red4[0] + red4[1] + red4[2] + red4[3];
            float sraw = fmaxf(sm + b2[0], 0.f);
            sc_s[v] = 1.f / (1.f + expf(-tanhf(fabsf(sraw))));
        }
        __syncthreads();
    }
    // ---- binning -> coeff (verified pattern) ----
    if (t < NG) { cnt[t] = 0; wsum[t] = 0.f; }
    __syncthreads();
    const int vn = vnum[n];
    const bool act = (t < NV) && (t < vn);
    float sc = 0.f; int b = 0;
    if (act) {
        sc = sc_s[t];
        b = (int)floorf(sc * 8.f); b = b < 0 ? 0 : (b > 7 ? 7 : b);
        atomicAdd(&cnt[b], 1);
    }
    __syncthreads();
    if (act) atomicAdd(&wsum[b], ceilf(sc * (float)cnt[b]));  // integer-valued: order-exact
    __syncthreads();
    if (t < NG) wt[t] = (cnt[t] > 0) ? wsum[t] / (float)cnt[t] : 0.f;
    __syncthreads();
    if (t == 0) { float x = 0.f; for (int g = 0; g < NG; ++g) x += wt[g]; wtotS = x; }
    __syncthreads();
    if (t < NV) coeffL[t] = act ? wt[b] / ((float)cnt[b] * wtotS) : 0.f;
    __syncthreads();
    // ---- desc ----
#pragma unroll
    for (int p = 0; p < 2; ++p) {
        int d = t + p * 512;
        float a = 0.f;
#pragma unroll
        for (int v = 0; v < NV; ++v)
            a = fmaf(coeffL[v], fv[((size_t)n * NV + v) * DFEAT + d], a);
        descL[d] = a;
    }
    __syncthreads();
    // ---- z1 slice: j = t&127, kq = t>>7 (4-way k split over 1024) ----
    {
        const int j = t & 127, kq = t >> 7;
        float a = 0.f;
#pragma unroll 8
        for (int dd = 0; dd < 256; ++dd) {
            int d = kq * 256 + dd;
            a = fmaf(descL[d], Wf1[(size_t)d * 512 + js + j], a);
        }
        zred[kq][j] = a;
    }
    __syncthreads();
    if (t < 128) {
        float s = zred[0][t] + zred[1][t] + zred[2][t] + zred[3][t];
        z1[n * 512 + js + t] = fmaxf(s + bf1[js + t], 0.f);
    }
}

// kB: z2 = relu(z1 @ Wf2 + bf2), out = z2 @ Wl + bl. One block per sample
// (k5f-verbatim epilogue).
__global__ __launch_bounds__(512)
void kB(const float* __restrict__ z1, const float* __restrict__ Wf2,
        const float* __restrict__ bf2, const float* __restrict__ Wl,
        const float* __restrict__ bl, float* __restrict__ out)
{
    const int n = blockIdx.x, t = threadIdx.x;
    __shared__ float z1L[512], z2L[256], outred[8][NCLS];
    z1L[t] = z1[n * 512 + t];
    __syncthreads();
    if (t < 256) {
        float a = 0.f;
#pragma unroll 8
        for (int d = 0; d < 512; ++d)
            a = fmaf(z1L[d], Wf2[(size_t)d * 256 + t], a);
        z2L[t] = fmaxf(a + bf2[t], 0.f);
    }
    __syncthreads();
    if (t < 320) {
        int j = t % NCLS, seg = t / NCLS;
        float a = 0.f;
#pragma unroll
        for (int dd = 0; dd < 32; ++dd) {
            int d = seg * 32 + dd;
            a = fmaf(z2L[d], Wl[d * NCLS + j], a);
        }
        outred[seg][j] = a;
    }
    __syncthreads();
    if (t < NCLS) {
        float a = bl[t];
#pragma unroll
        for (int s8 = 0; s8 < 8; ++s8) a += outred[s8][t];
        out[n * NCLS + t] = a;
    }
}

extern "C" void kernel_launch(void* const* d_in, const int* in_sizes, int n_in,
                              void* d_out, int out_size, void* d_ws, size_t ws_size,
                              hipStream_t stream)
{
    const float* raw  = (const float*)d_in[0];
    const float* fv   = (const float*)d_in[1];
    const int*   vnum = (const int*)d_in[2];
    const float* W1   = (const float*)d_in[3];
    const float* b1   = (const float*)d_in[4];
    const float* W2   = (const float*)d_in[5];
    const float* b2   = (const float*)d_in[6];
    const float* Wf1  = (const float*)d_in[7];
    const float* bf1  = (const float*)d_in[8];
    const float* Wf2  = (const float*)d_in[9];
    const float* bf2  = (const float*)d_in[10];
    const float* Wl   = (const float*)d_in[11];
    const float* bl   = (const float*)d_in[12];
    float* out = (float*)d_out;
    char* ws = (char*)d_ws;
    float* part = (float*)(ws + WS_PART);
    float* hr   = (float*)(ws + WS_HR);
    float* z1   = (float*)(ws + WS_Z1);

    k1_mfma<<<NCHUNK, 512, 0, stream>>>(raw, W1, vnum, part);
    k2_half<<<2 * NROWS, 1024, 0, stream>>>(part, hr);
    kA<<<4 * NB, 512, 0, stream>>>(hr, b1, W2, b2, vnum, fv, Wf1, bf1, z1);
    kB<<<NB, 512, 0, stream>>>(z1, Wf2, bf2, Wl, bl, out);
}